// Round 5
// baseline (400.338 us; speedup 1.0000x reference)
//
#include <hip/hip_runtime.h>

#define NN 100000
#define NE 1600000
#define HID 32
#define NBK 98          // ceil(NN/1024) buckets of 1024 nodes
#define CHUNK 4096      // edges per partition block
#define NSLAB 7         // src slab = src >> 14 (16384 nodes = 2 MB of rows)
#define KEYS 8192       // 1024 local nodes x 8 (slab stride 8)
#define GPB 64          // nodes per conv block

// ---- count edges per 1024-node bucket (LDS hist -> global atomics) ----
__global__ void bucket_count_kernel(const int* __restrict__ dst, int* __restrict__ bktcnt) {
    __shared__ int hist[NBK];
    int t = threadIdx.x;
    int base = blockIdx.x * CHUNK;
    int end = min(base + CHUNK, NE);
    if (t < NBK) hist[t] = 0;
    __syncthreads();
    for (int e = base + t; e < end; e += 256)
        atomicAdd(&hist[dst[e] >> 10], 1);
    __syncthreads();
    if (t < NBK && hist[t]) atomicAdd(&bktcnt[t], hist[t]);
}

// ---- exclusive scan of 98 bucket counts ----
__global__ void bucket_scan_kernel(const int* __restrict__ bktcnt, int* __restrict__ bktbase,
                                   int* __restrict__ bktcur) {
    __shared__ int ls[128];
    int t = threadIdx.x;
    int v = (t < NBK) ? bktcnt[t] : 0;
    ls[t] = v;
    __syncthreads();
    for (int off = 1; off < 128; off <<= 1) {
        int x = (t >= off) ? ls[t - off] : 0;
        __syncthreads();
        ls[t] += x;
        __syncthreads();
    }
    int excl = ls[t] - v;
    if (t < NBK) { bktbase[t] = excl; bktcur[t] = excl; }
    if (t == 0) bktbase[NBK] = NE;
}

// ---- partition edges into bucket-ordered packed array: (src<<10)|dst_local ----
__global__ void partA_kernel(const int* __restrict__ src, const int* __restrict__ dst,
                             int* __restrict__ bktcur, int* __restrict__ bedges) {
    __shared__ int hist[NBK];
    __shared__ int lofs[NBK];
    int t = threadIdx.x;
    int base = blockIdx.x * CHUNK;
    int end = min(base + CHUNK, NE);
    if (t < NBK) hist[t] = 0;
    __syncthreads();
    for (int e = base + t; e < end; e += 256)
        atomicAdd(&hist[dst[e] >> 10], 1);
    __syncthreads();
    if (t < NBK) lofs[t] = hist[t] ? atomicAdd(&bktcur[t], hist[t]) : 0;
    __syncthreads();
    for (int e = base + t; e < end; e += 256) {
        int d = dst[e], s = src[e];
        int p = atomicAdd(&lofs[d >> 10], 1);
        bedges[p] = (s << 10) | (d & 1023);
    }
}

// ---- per-bucket: 8192-key (node,slab) hist -> scan -> rowstart2/dinv -> binning ----
__global__ __launch_bounds__(512) void bucket_build_kernel(
        const int* __restrict__ bedges, const int* __restrict__ bktbase,
        int* __restrict__ rowstart2, float* __restrict__ dinv, int* __restrict__ srcidx) {
    __shared__ int lcnt[KEYS];
    __shared__ int wsum[512];
    int b = blockIdx.x, t = threadIdx.x;
    int ebeg = bktbase[b], eend = bktbase[b + 1];
#pragma unroll
    for (int i = 0; i < KEYS / 512; ++i) lcnt[t + 512 * i] = 0;
    __syncthreads();
    for (int e = ebeg + t; e < eend; e += 512) {
        int p = bedges[e];
        int key = ((p & 1023) << 3) | ((unsigned)p >> 24);  // (local_dst, slab)
        atomicAdd(&lcnt[key], 1);
    }
    __syncthreads();
    // hierarchical exclusive scan: thread t owns keys 16t..16t+15 (= 2 nodes)
    int c[16];
    int tot = 0;
    int k0 = t << 4;
#pragma unroll
    for (int i = 0; i < 16; ++i) { c[i] = lcnt[k0 + i]; tot += c[i]; }
    wsum[t] = tot;
    __syncthreads();
    for (int off = 1; off < 512; off <<= 1) {
        int x = (t >= off) ? wsum[t - off] : 0;
        __syncthreads();
        wsum[t] += x;
        __syncthreads();
    }
    int run = wsum[t] - tot;
    int gbase = (b << 13) + k0;
#pragma unroll
    for (int i = 0; i < 16; ++i) {
        lcnt[k0 + i] = run;                 // becomes bin cursor
        rowstart2[gbase + i] = ebeg + run;
        run += c[i];
    }
    int n = (b << 10) + (t << 1);
    if (n < NN) {
        int d0 = c[0] + c[1] + c[2] + c[3] + c[4] + c[5] + c[6] + c[7];
        dinv[n] = rsqrtf((float)(d0 + 1));
    }
    if (n + 1 < NN) {
        int d1 = c[8] + c[9] + c[10] + c[11] + c[12] + c[13] + c[14] + c[15];
        dinv[n + 1] = rsqrtf((float)(d1 + 1));
    }
    __syncthreads();
    for (int e = ebeg + t; e < eend; e += 512) {
        int p = bedges[e];
        int key = ((p & 1023) << 3) | ((unsigned)p >> 24);
        int pos = atomicAdd(&lcnt[key], 1);
        srcidx[ebeg + pos] = (unsigned)p >> 10;
    }
}

// ---- fc1: hs[n,j] = relu(x@W + b) * dinv[n]  (pre-scaled activations) ----
__global__ void fc1_kernel(const float* __restrict__ x, const float* __restrict__ W,
                           const float* __restrict__ b, const float* __restrict__ dinv,
                           float* __restrict__ hs) {
    int gid = blockIdx.x * blockDim.x + threadIdx.x;
    if (gid >= NN * HID) return;
    int n = gid >> 5, j = gid & 31;
    float v = x[2 * n] * W[j] + x[2 * n + 1] * W[HID + j] + b[j];
    hs[gid] = fmaxf(v, 0.f) * dinv[n];
}

// ---- slab-phased conv: 64 nodes/block, lane=channel, acc in regs, LDS GEMM epilogue ----
template <bool OUTSCALE>
__global__ __launch_bounds__(256, 8) void conv_slab_kernel(
        const float* __restrict__ hs_in, const int* __restrict__ rs2,
        const int* __restrict__ srcidx, const float* __restrict__ dinv,
        const float* __restrict__ W, const float* __restrict__ bias,
        float* __restrict__ hs_out) {
    __shared__ float wl[HID * HID];
    __shared__ float agg[GPB][HID];
    int tid = threadIdx.x;
#pragma unroll
    for (int i = 0; i < 4; ++i) wl[tid + 256 * i] = W[tid + 256 * i];
    int w = tid >> 6, lane = tid & 63, half = lane >> 5, ch = lane & 31;
    int nb = blockIdx.x * GPB;
    float acc[8];
#pragma unroll
    for (int q = 0; q < 8; ++q) acc[q] = 0.f;
    for (int p = 0; p < NSLAB; ++p) {
#pragma unroll
        for (int q = 0; q < 8; ++q) {
            int n = nb + w * 16 + q * 2 + half;
            if (n < NN) {
                int beg = rs2[n * 8 + p], end = rs2[n * 8 + p + 1];
                float a0 = 0.f, a1 = 0.f;
                int e = beg;
                for (; e + 1 < end; e += 2) {
                    int s0 = srcidx[e], s1 = srcidx[e + 1];
                    a0 += hs_in[(s0 << 5) + ch];
                    a1 += hs_in[(s1 << 5) + ch];
                }
                if (e < end) a0 += hs_in[(srcidx[e] << 5) + ch];
                acc[q] += a0 + a1;
            }
        }
    }
#pragma unroll
    for (int q = 0; q < 8; ++q) {
        int ln = w * 16 + q * 2 + half;
        int n = nb + ln;
        if (n < NN) agg[ln][ch] = (acc[q] + hs_in[(n << 5) + ch]) * dinv[n];
    }
    __syncthreads();
    int j = tid & 31;
#pragma unroll
    for (int r = 0; r < 8; ++r) {
        int ln = (tid >> 5) + r * 8;
        int n = nb + ln;
        if (n >= NN) continue;
        float v = 0.f;
#pragma unroll
        for (int k = 0; k < HID; ++k) v += agg[ln][k] * wl[k * HID + j];
        v = fmaxf(v + bias[j], 0.f);
        if (OUTSCALE) v *= dinv[n];
        hs_out[(n << 5) + j] = v;
    }
}

// ---- fused fc2+fc3 ----
__global__ void fc23_kernel(const float* __restrict__ h, const float* __restrict__ W2,
                            const float* __restrict__ b2, const float* __restrict__ W3,
                            const float* __restrict__ b3, float* __restrict__ out) {
    __shared__ float wl[HID * HID];
    __shared__ float hsl[256];
    int tid = threadIdx.x;
    int base = blockIdx.x * 256;
#pragma unroll
    for (int i = 0; i < 4; ++i) wl[tid + 256 * i] = W2[tid + 256 * i];
    hsl[tid] = h[base + tid];
    __syncthreads();
    int ln = tid >> 5, j = tid & 31;
    float v = 0.f;
#pragma unroll
    for (int k = 0; k < HID; ++k) v += hsl[ln * HID + k] * wl[k * HID + j];
    v = fmaxf(v + b2[j], 0.f);
    float p = v * W3[j];
#pragma unroll
    for (int m = 16; m; m >>= 1) p += __shfl_xor(p, m);
    if (j == 0) out[(base >> 5) + ln] = p + b3[0];
}

extern "C" void kernel_launch(void* const* d_in, const int* in_sizes, int n_in,
                              void* d_out, int out_size, void* d_ws, size_t ws_size,
                              hipStream_t stream) {
    const float* x     = (const float*)d_in[0];
    const int*   ei    = (const int*)d_in[1];
    const float* fc1_W = (const float*)d_in[2];
    const float* fc1_b = (const float*)d_in[3];
    const float* c1_W  = (const float*)d_in[4];
    const float* c1_b  = (const float*)d_in[5];
    const float* c2_W  = (const float*)d_in[6];
    const float* c2_b  = (const float*)d_in[7];
    const float* c3_W  = (const float*)d_in[8];
    const float* c3_b  = (const float*)d_in[9];
    const float* fc2_W = (const float*)d_in[10];
    const float* fc2_b = (const float*)d_in[11];
    const float* fc3_W = (const float*)d_in[12];
    const float* fc3_b = (const float*)d_in[13];

    const int* src = ei;
    const int* dst = ei + NE;

    // workspace layout
    float* ws        = (float*)d_ws;
    float* dinv      = ws;                               // NN
    float* hA        = ws + NN;                          // NN*32
    float* hB        = hA + NN * HID;                    // NN*32
    int*   rowstart2 = (int*)(hB + NN * HID);            // NBK*1024*8 + 8
    int*   srcidx    = rowstart2 + NBK * 1024 * 8 + 8;   // NE
    int*   bktcnt    = srcidx + NE;                      // NBK
    int*   bktbase   = bktcnt + NBK;                     // NBK+1
    int*   bktcur    = bktbase + NBK + 1;                // NBK
    int*   bedges    = (int*)hA;                         // NE (alias; used pre-fc1)

    float* out = (float*)d_out;

    const int B = 256;
    const int gNH = (NN * HID + B - 1) / B;              // 12500
    const int gPart = (NE + CHUNK - 1) / CHUNK;          // 391
    const int gConv = (NN + GPB - 1) / GPB;              // 1563

    // ---- build slab-segmented CSR ----
    hipMemsetAsync(bktcnt, 0, NBK * sizeof(int), stream);
    bucket_count_kernel<<<gPart, B, 0, stream>>>(dst, bktcnt);
    bucket_scan_kernel<<<1, 128, 0, stream>>>(bktcnt, bktbase, bktcur);
    partA_kernel<<<gPart, B, 0, stream>>>(src, dst, bktcur, bedges);
    bucket_build_kernel<<<NBK, 512, 0, stream>>>(bedges, bktbase, rowstart2, dinv, srcidx);

    // fc1 -> hA (pre-scaled by dinv)
    fc1_kernel<<<gNH, B, 0, stream>>>(x, fc1_W, fc1_b, dinv, hA);

    // conv1..3 (slab-phased gather + GEMM)
    conv_slab_kernel<true><<<gConv, B, 0, stream>>>(hA, rowstart2, srcidx, dinv, c1_W, c1_b, hB);
    conv_slab_kernel<true><<<gConv, B, 0, stream>>>(hB, rowstart2, srcidx, dinv, c2_W, c2_b, hA);
    conv_slab_kernel<false><<<gConv, B, 0, stream>>>(hA, rowstart2, srcidx, dinv, c3_W, c3_b, hB);

    // fc2+fc3 -> out
    fc23_kernel<<<gNH, B, 0, stream>>>(hB, fc2_W, fc2_b, fc3_W, fc3_b, out);
}